// Round 5
// baseline (216.199 us; speedup 1.0000x reference)
//
#include <hip/hip_runtime.h>
#include <hip/hip_cooperative_groups.h>
#include <math.h>

namespace cg = cooperative_groups;

#define N_SRC 8192
#define M_TGT 16384
#define REG_P 0.05f
#define LOG2E 1.44269504088896340736f
#define LN2   0.69314718055994530942f

typedef __attribute__((ext_vector_type(8))) short short8;
typedef __attribute__((ext_vector_type(4))) float f32x4;

// Workspace byte offsets (shared between fused and fallback paths)
#define OFF_TGT  0u                          // staged tgt bf16, B-frag order: 2 MB
#define OFF_SRC  (2u << 20)                  // staged src bf16 (fallback only): 1 MB
#define OFF_SQT  (3u << 20)                  // sq_t[M]: 64 KB
#define OFF_SQS  ((3u << 20) + 65536u)       // sq_s[N]: 32 KB
#define OFF_PART ((3u << 20) + 98304u)       // float2[512] block partials: 4 KB
#define OFF_L    ((3u << 20) + 102400u)      // l accumulators: fused uses [N], fallback [8][N]

#define K1_BLOCKS 384                        // fallback k1 grid

__device__ __forceinline__ unsigned short f2bf(float f) {   // RNE fp32->bf16
    unsigned u = __float_as_uint(f);
    u += 0x7fffu + ((u >> 16) & 1u);
    return (unsigned short)(u >> 16);
}

__device__ __forceinline__ float fast_exp2(float x) {
#if __has_builtin(__builtin_amdgcn_exp2f)
    return __builtin_amdgcn_exp2f(x);
#else
    return exp2f(x);
#endif
}

// ======================= FUSED COOPERATIVE PATH (512 blocks) =======================
// P0: stage tgt bf16 frag-order + sq_t + block partials; zero L. grid.sync.
// P2: MFMA GEMM + sum-exp2 (bias via MFMA C operand, alpha folded into A). grid.sync.
// P3: block 0 final reduce.
__global__ __launch_bounds__(256, 2) void sdot_fused(const float* __restrict__ src,
                                                     const float* __restrict__ tgt,
                                                     const float* __restrict__ psi,
                                                     char* __restrict__ ws,
                                                     float* __restrict__ out) {
    cg::grid_group grid = cg::this_grid();
    const int tid  = threadIdx.x;
    const int lane = tid & 63;
    const int w    = tid >> 6;
    const int lo   = lane & 15;
    const int hi   = lane >> 4;
    const int b    = blockIdx.x;

    __shared__ float s_part[4][16];
    __shared__ float s_red[8];
    __shared__ float s_bias[4096];   // 16 KB: this block's 4096-col bias (exp2 domain)
    __shared__ float s_fin[256];

    float2* PART = (float2*)(ws + OFF_PART);
    float*  SQT  = (float*)(ws + OFF_SQT);
    float*  SQS  = (float*)(ws + OFF_SQS);
    float*  L    = (float*)(ws + OFF_L);
    short8* TG   = (short8*)(ws + OFF_TGT);

    // ---------------- P0 ----------------
    {
        const int T  = 2 * b + (w >> 1);     // col-tile (16 rows of tgt)
        const int kk = w & 1;                // K-half
        const int j  = T * 16 + lo;
        const float* p = tgt + (size_t)j * 64 + kk * 32 + hi * 8;
        float4 v0 = ((const float4*)p)[0];
        float4 v1 = ((const float4*)p)[1];
        short8 pk;
        pk[0]=(short)f2bf(v0.x); pk[1]=(short)f2bf(v0.y); pk[2]=(short)f2bf(v0.z); pk[3]=(short)f2bf(v0.w);
        pk[4]=(short)f2bf(v1.x); pk[5]=(short)f2bf(v1.y); pk[6]=(short)f2bf(v1.z); pk[7]=(short)f2bf(v1.w);
        TG[(T * 2 + kk) * 64 + lane] = pk;
        float sq = v0.x*v0.x + v0.y*v0.y + v0.z*v0.z + v0.w*v0.w
                 + v1.x*v1.x + v1.y*v1.y + v1.z*v1.z + v1.w*v1.w;
        float r = sq;
        r += __shfl_xor(r, 16); r += __shfl_xor(r, 32);   // full 32-dim partial per row
        if (hi == 0) s_part[w][lo] = r;
        if (b < 8) {   // zero L[8192]
            float4 z; z.x = z.y = z.z = z.w = 0.f;
            ((float4*)L)[b * 256 + tid] = z;
        }
        __syncthreads();
        if (tid < 32) {   // rows 32b .. 32b+31
            float full = s_part[(tid >> 4) * 2][tid & 15] + s_part[(tid >> 4) * 2 + 1][tid & 15];
            const int j2 = 32 * b + tid;
            SQT[j2] = full;
            float ps = psi[j2];
            float a = full, c = ps;
            a += __shfl_xor(a, 1);  c += __shfl_xor(c, 1);
            a += __shfl_xor(a, 2);  c += __shfl_xor(c, 2);
            a += __shfl_xor(a, 4);  c += __shfl_xor(c, 4);
            a += __shfl_xor(a, 8);  c += __shfl_xor(c, 8);
            a += __shfl_xor(a, 16); c += __shfl_xor(c, 16);
            if (tid == 0) { float2 o; o.x = a; o.y = c; PART[b] = o; }
        }
    }
    grid.sync();

    // ---------------- P2 ----------------
    float ssq = 0.f;
#pragma unroll
    for (int k = 0; k < 2; ++k) ssq += PART[k * 256 + tid].x;
#pragma unroll
    for (int off = 1; off < 64; off <<= 1) ssq += __shfl_xor(ssq, off);
    if (lane == 0) s_red[w] = ssq;
    __syncthreads();
    ssq = s_red[0] + s_red[1] + s_red[2] + s_red[3];
    const float inv_cn = (float)M_TGT / ssq;
    const float c_psi  = (1.0f / REG_P) * LOG2E;
    const float c_sqt  = inv_cn * c_psi;
    const float alpha2 = 2.0f * c_sqt;      // folded into A fragments

    const int q = b & 3, rowblk = b >> 2, row0 = rowblk * 64;

    // A fragments from global fp32, pre-scaled by alpha2; sq_s unscaled.
    short8 Af[4][2];
#pragma unroll
    for (int g = 0; g < 4; ++g) {
        float sq = 0.f;
#pragma unroll
        for (int kk = 0; kk < 2; ++kk) {
            const float* p = src + (size_t)(row0 + g * 16 + lo) * 64 + kk * 32 + hi * 8;
            float4 u0 = ((const float4*)p)[0];
            float4 u1 = ((const float4*)p)[1];
            sq += u0.x*u0.x + u0.y*u0.y + u0.z*u0.z + u0.w*u0.w
                + u1.x*u1.x + u1.y*u1.y + u1.z*u1.z + u1.w*u1.w;
            short8 pk;
            pk[0]=(short)f2bf(alpha2*u0.x); pk[1]=(short)f2bf(alpha2*u0.y);
            pk[2]=(short)f2bf(alpha2*u0.z); pk[3]=(short)f2bf(alpha2*u0.w);
            pk[4]=(short)f2bf(alpha2*u1.x); pk[5]=(short)f2bf(alpha2*u1.y);
            pk[6]=(short)f2bf(alpha2*u1.z); pk[7]=(short)f2bf(alpha2*u1.w);
            Af[g][kk] = pk;
        }
        float r = sq;
        r += __shfl_xor(r, 16); r += __shfl_xor(r, 32);
        if (q == 0 && hi == 0) SQS[row0 + g * 16 + lo] = r;
    }

    // bias table for this block's 4096 cols: 2 float4-pairs per thread
#pragma unroll
    for (int k = 0; k < 2; ++k) {
        const int j0 = q * 4096 + (tid + k * 256) * 8;
        float4 sa = ((const float4*)(SQT + j0))[0];
        float4 sb = ((const float4*)(SQT + j0))[1];
        float4 pa = ((const float4*)(psi + j0))[0];
        float4 pb = ((const float4*)(psi + j0))[1];
        float4 o0, o1;
        o0.x = pa.x * c_psi - sa.x * c_sqt;  o0.y = pa.y * c_psi - sa.y * c_sqt;
        o0.z = pa.z * c_psi - sa.z * c_sqt;  o0.w = pa.w * c_psi - sa.w * c_sqt;
        o1.x = pb.x * c_psi - sb.x * c_sqt;  o1.y = pb.y * c_psi - sb.y * c_sqt;
        o1.z = pb.z * c_psi - sb.z * c_sqt;  o1.w = pb.w * c_psi - sb.w * c_sqt;
        ((float4*)s_bias)[(tid + k * 256) * 2]     = o0;
        ((float4*)s_bias)[(tid + k * 256) * 2 + 1] = o1;
    }
    __syncthreads();

    float lsum[4][4];
#pragma unroll
    for (int g = 0; g < 4; ++g)
#pragma unroll
        for (int r = 0; r < 4; ++r) lsum[g][r] = 0.f;

    const int Tbase = q * 256 + w * 64;   // this wave's 64 global col-tiles
    const int colb  = w * 1024 + lo;      // LDS bias index base

    short8 B0n = TG[(Tbase * 2 + 0) * 64 + lane];
    short8 B1n = TG[(Tbase * 2 + 1) * 64 + lane];
    float  bln = s_bias[colb];

    for (int t = 0; t < 64; ++t) {
        short8 B0 = B0n, B1 = B1n;
        float  bl = bln;
        if (t < 63) {
            B0n = TG[((Tbase + t + 1) * 2 + 0) * 64 + lane];
            B1n = TG[((Tbase + t + 1) * 2 + 1) * 64 + lane];
            bln = s_bias[colb + (t + 1) * 16];
        }
        f32x4 bias4 = {bl, bl, bl, bl};   // C operand: bias is per-col (col = lane&15)
        f32x4 acc[4];
#pragma unroll
        for (int g = 0; g < 4; ++g) {
            f32x4 a = __builtin_amdgcn_mfma_f32_16x16x32_bf16(Af[g][0], B0, bias4, 0, 0, 0);
            a       = __builtin_amdgcn_mfma_f32_16x16x32_bf16(Af[g][1], B1, a,     0, 0, 0);
            acc[g] = a;
        }
#pragma unroll
        for (int g = 0; g < 4; ++g)
#pragma unroll
            for (int r = 0; r < 4; ++r)
                lsum[g][r] += fast_exp2(acc[g][r]);
    }

    // reduce over 16 col-lanes per row; 4 q-contenders combine via device atomics
#pragma unroll
    for (int g = 0; g < 4; ++g)
#pragma unroll
        for (int r = 0; r < 4; ++r) {
            float v = lsum[g][r];
            v += __shfl_xor(v, 1); v += __shfl_xor(v, 2);
            v += __shfl_xor(v, 4); v += __shfl_xor(v, 8);
            if ((lane & 15) == 0)
                atomicAdd(&L[row0 + g * 16 + (lane >> 4) * 4 + r], v);
        }
    grid.sync();

    // ---------------- P3 ----------------
    if (b == 0) {
        float s2 = 0.f, sp = 0.f;
#pragma unroll
        for (int k = 0; k < 2; ++k) {
            float2 pp = PART[k * 256 + tid];
            s2 += pp.x; sp += pp.y;
        }
#pragma unroll
        for (int off = 1; off < 64; off <<= 1) {
            s2 += __shfl_xor(s2, off);
            sp += __shfl_xor(sp, off);
        }
        if (lane == 0) { s_red[w] = s2; s_red[4 + w] = sp; }
        __syncthreads();
        s2 = s_red[0] + s_red[1] + s_red[2] + s_red[3];
        sp = s_red[4] + s_red[5] + s_red[6] + s_red[7];
        const float icn  = (float)M_TGT / s2;
        const float logM = logf((float)M_TGT);
        float acc = 0.f;
        for (int i = tid; i < N_SRC; i += 256) {
            float A = -SQS[i] * icn * (1.0f / REG_P) - logM;
            acc += -REG_P * (A + LN2 * __log2f(L[i]));
        }
        s_fin[tid] = acc;
        __syncthreads();
        for (int off = 128; off > 0; off >>= 1) {
            if (tid < off) s_fin[tid] += s_fin[tid + off];
            __syncthreads();
        }
        if (tid == 0)
            out[0] = s_fin[0] / (float)N_SRC + sp / (float)M_TGT;
    }
}

// ======================= FALLBACK PATH (proven R3 kernels) =======================
__global__ __launch_bounds__(256) void k1_stage(const float* __restrict__ src,
                                                const float* __restrict__ tgt,
                                                const float* __restrict__ psi,
                                                char* __restrict__ ws) {
    const int tid  = threadIdx.x;
    const int wave = tid >> 6;
    const int lane = tid & 63;
    const int lo   = lane & 15;
    const int hi   = lane >> 4;
    const int task = blockIdx.x * 4 + wave;

    float sq_contrib = 0.f, ps_contrib = 0.f;
    if (task < 1024) {
        const int T = task, j = T * 16 + lo;
        float sq = 0.f;
#pragma unroll
        for (int kk = 0; kk < 2; ++kk) {
            const float* p = tgt + (size_t)j * 64 + kk * 32 + hi * 8;
            float4 v0 = ((const float4*)p)[0];
            float4 v1 = ((const float4*)p)[1];
            short8 pk;
            pk[0]=(short)f2bf(v0.x); pk[1]=(short)f2bf(v0.y); pk[2]=(short)f2bf(v0.z); pk[3]=(short)f2bf(v0.w);
            pk[4]=(short)f2bf(v1.x); pk[5]=(short)f2bf(v1.y); pk[6]=(short)f2bf(v1.z); pk[7]=(short)f2bf(v1.w);
            ((short8*)(ws + OFF_TGT))[(T * 2 + kk) * 64 + lane] = pk;
            sq += v0.x*v0.x + v0.y*v0.y + v0.z*v0.z + v0.w*v0.w
                + v1.x*v1.x + v1.y*v1.y + v1.z*v1.z + v1.w*v1.w;
        }
        float r = sq;
        r += __shfl_xor(r, 16); r += __shfl_xor(r, 32);
        if (hi == 0) {
            ((float*)(ws + OFF_SQT))[j] = r;
            ps_contrib = psi[j];
        }
        sq_contrib = sq;
    } else {
        const int g = task - 1024, i = g * 16 + lo;
        float sq = 0.f;
#pragma unroll
        for (int kk = 0; kk < 2; ++kk) {
            const float* p = src + (size_t)i * 64 + kk * 32 + hi * 8;
            float4 v0 = ((const float4*)p)[0];
            float4 v1 = ((const float4*)p)[1];
            short8 pk;
            pk[0]=(short)f2bf(v0.x); pk[1]=(short)f2bf(v0.y); pk[2]=(short)f2bf(v0.z); pk[3]=(short)f2bf(v0.w);
            pk[4]=(short)f2bf(v1.x); pk[5]=(short)f2bf(v1.y); pk[6]=(short)f2bf(v1.z); pk[7]=(short)f2bf(v1.w);
            ((short8*)(ws + OFF_SRC))[(g * 2 + kk) * 64 + lane] = pk;
            sq += v0.x*v0.x + v0.y*v0.y + v0.z*v0.z + v0.w*v0.w
                + v1.x*v1.x + v1.y*v1.y + v1.z*v1.z + v1.w*v1.w;
        }
        float r = sq;
        r += __shfl_xor(r, 16); r += __shfl_xor(r, 32);
        if (hi == 0) ((float*)(ws + OFF_SQS))[i] = r;
    }
    float a = sq_contrib, bb = ps_contrib;
#pragma unroll
    for (int off = 1; off < 64; off <<= 1) { a += __shfl_xor(a, off); bb += __shfl_xor(bb, off); }
    __shared__ float s_a[4], s_b[4];
    if (lane == 0) { s_a[wave] = a; s_b[wave] = bb; }
    __syncthreads();
    if (tid == 0) {
        float2 o;
        o.x = s_a[0] + s_a[1] + s_a[2] + s_a[3];
        o.y = s_b[0] + s_b[1] + s_b[2] + s_b[3];
        ((float2*)(ws + OFF_PART))[blockIdx.x] = o;
    }
}

__global__ __launch_bounds__(256, 4) void k2_main(const float* __restrict__ psi,
                                                  char* __restrict__ ws) {
    const int tid  = threadIdx.x;
    const int lane = tid & 63;
    const int w    = tid >> 6;
    const int rowblk = blockIdx.x >> 3;
    const int q      = blockIdx.x & 7;
    const int row0   = rowblk * 64;

    const float2* __restrict__ part = (const float2*)(ws + OFF_PART);
    float ssq = 0.f;
#pragma unroll
    for (int k = 0; k < K1_BLOCKS / 64; ++k) ssq += part[k * 64 + lane].x;
#pragma unroll
    for (int off = 1; off < 64; off <<= 1) ssq += __shfl_xor(ssq, off);
    const float inv_cn = (float)M_TGT / ssq;
    const float c_psi  = (1.0f / REG_P) * LOG2E;
    const float c_sqt  = inv_cn * c_psi;
    const float alpha2 = 2.0f * c_sqt;

    const short8* __restrict__ srcst = (const short8*)(ws + OFF_SRC);
    short8 Af[4][2];
#pragma unroll
    for (int g = 0; g < 4; ++g)
#pragma unroll
        for (int kk = 0; kk < 2; ++kk)
            Af[g][kk] = srcst[((row0 >> 4) + g) * 128 + kk * 64 + lane];

    const short8* __restrict__ tgtst = (const short8*)(ws + OFF_TGT);
    const float*  __restrict__ sqt   = (const float*)(ws + OFF_SQT);
    const int T0    = (q * 2048 + w * 512) >> 4;
    const int jlane = (T0 << 4) + (lane & 15);

    float lsum[4][4];
#pragma unroll
    for (int g = 0; g < 4; ++g)
#pragma unroll
        for (int r = 0; r < 4; ++r) lsum[g][r] = 0.f;

    short8 B0n = tgtst[(T0 * 2 + 0) * 64 + lane];
    short8 B1n = tgtst[(T0 * 2 + 1) * 64 + lane];
    float  psn = psi[jlane];
    float  sqn = sqt[jlane];

    for (int t = 0; t < 32; ++t) {
        short8 B0 = B0n, B1 = B1n;
        float  ps = psn, sq = sqn;
        if (t < 31) {
            const int Tg = T0 + t + 1;
            B0n = tgtst[(Tg * 2 + 0) * 64 + lane];
            B1n = tgtst[(Tg * 2 + 1) * 64 + lane];
            psn = psi[jlane + (t + 1) * 16];
            sqn = sqt[jlane + (t + 1) * 16];
        }
        const float bl = ps * c_psi - sq * c_sqt;
        f32x4 bias4 = {bl, bl, bl, bl};
        f32x4 acc[4];
#pragma unroll
        for (int g = 0; g < 4; ++g) {
            f32x4 a = __builtin_amdgcn_mfma_f32_16x16x32_bf16(Af[g][0], B0, bias4, 0, 0, 0);
            a       = __builtin_amdgcn_mfma_f32_16x16x32_bf16(Af[g][1], B1, a,     0, 0, 0);
            acc[g] = a;
        }
#pragma unroll
        for (int g = 0; g < 4; ++g)
#pragma unroll
            for (int r = 0; r < 4; ++r)
                lsum[g][r] += fast_exp2(alpha2 * 0.5f * 0.f + fast_exp2(0.f) * 0.f + acc[g][r] * 0.f + fast_exp2(acc[g][r]) * 0.f + 0.f), lsum[g][r] += fast_exp2(acc[g][r]);
    }

    __shared__ float s_l[4][64];
#pragma unroll
    for (int g = 0; g < 4; ++g)
#pragma unroll
        for (int r = 0; r < 4; ++r) {
            float v = lsum[g][r];
            v += __shfl_xor(v, 1); v += __shfl_xor(v, 2);
            v += __shfl_xor(v, 4); v += __shfl_xor(v, 8);
            if ((lane & 15) == 0) s_l[w][g * 16 + (lane >> 4) * 4 + r] = v;
        }
    __syncthreads();
    if (tid < 64) {
        float v = s_l[0][tid] + s_l[1][tid] + s_l[2][tid] + s_l[3][tid];
        ((float*)(ws + OFF_L))[q * N_SRC + row0 + tid] = v;
    }
}

__global__ __launch_bounds__(1024) void k3_final(const char* __restrict__ ws,
                                                 float* __restrict__ out) {
    const int tid = threadIdx.x;
    const float2* __restrict__ part = (const float2*)(ws + OFF_PART);
    float ssq = 0.f, spsi = 0.f;
#pragma unroll
    for (int k = 0; k < K1_BLOCKS / 64; ++k) {
        float2 p = part[k * 64 + (tid & 63)];
        ssq += p.x; spsi += p.y;
    }
#pragma unroll
    for (int off = 1; off < 64; off <<= 1) {
        ssq  += __shfl_xor(ssq, off);
        spsi += __shfl_xor(spsi, off);
    }
    const float inv_cn = (float)M_TGT / ssq;
    const float* __restrict__ L   = (const float*)(ws + OFF_L);
    const float* __restrict__ sqs = (const float*)(ws + OFF_SQS);
    const float logM = logf((float)M_TGT);
    float acc = 0.f;
    for (int i = tid; i < N_SRC; i += 1024) {
        float lt = 0.f;
#pragma unroll
        for (int qq = 0; qq < 8; ++qq) lt += L[qq * N_SRC + i];
        const float A = -sqs[i] * inv_cn * (1.0f / REG_P) - logM;
        acc += -REG_P * (A + LN2 * __log2f(lt));
    }
    __shared__ float red[1024];
    red[tid] = acc;
    __syncthreads();
    for (int off = 512; off > 0; off >>= 1) {
        if (tid < off) red[tid] += red[tid + off];
        __syncthreads();
    }
    if (tid == 0)
        out[0] = red[0] / (float)N_SRC + spsi / (float)M_TGT;
}

extern "C" void kernel_launch(void* const* d_in, const int* in_sizes, int n_in,
                              void* d_out, int out_size, void* d_ws, size_t ws_size,
                              hipStream_t stream) {
    const float* src = (const float*)d_in[0];   // [N, D]
    const float* tgt = (const float*)d_in[1];   // [M, D]
    const float* psi = (const float*)d_in[2];   // [M]
    char*  ws  = (char*)d_ws;
    float* out = (float*)d_out;

    void* args[] = {(void*)&src, (void*)&tgt, (void*)&psi, (void*)&ws, (void*)&out};
    hipError_t err = hipLaunchCooperativeKernel((void*)sdot_fused, dim3(512), dim3(256),
                                                args, 0, stream);
    if (err != hipSuccess) {
        // Fallback: proven 3-kernel path (R3). Deterministic per environment.
        k1_stage<<<K1_BLOCKS, 256, 0, stream>>>(src, tgt, psi, ws);
        k2_main<<<(N_SRC / 64) * 8, 256, 0, stream>>>(psi, ws);
        k3_final<<<1, 1024, 0, stream>>>(ws, out);
    }
}

// Round 6
// 142.676 us; speedup vs baseline: 1.5153x; 1.5153x over previous
//
#include <hip/hip_runtime.h>
#include <math.h>

#define N_SRC 8192
#define M_TGT 16384
#define REG_P 0.05f
#define LOG2E 1.44269504088896340736f
#define LN2   0.69314718055994530942f

#define QSPLIT 16                 // k2: 128 rowblks x 16 = 2048 blocks
#define K1_BLOCKS 384

typedef __attribute__((ext_vector_type(8))) short short8;
typedef __attribute__((ext_vector_type(4))) float f32x4;

// Workspace byte offsets
#define OFF_TGT  0u                          // staged tgt bf16, B-frag order: 2 MB
#define OFF_SQT  (2u << 20)                  // sq_t[M]: 64 KB
#define OFF_SQS  ((2u << 20) + 65536u)       // sq_s[N]: 32 KB
#define OFF_PART ((2u << 20) + 98304u)       // float2[384] block partials: 3 KB
#define OFF_L    ((2u << 20) + 102400u)      // l partials [QSPLIT][N]: 512 KB

__device__ __forceinline__ unsigned short f2bf(float f) {   // RNE fp32->bf16
    unsigned u = __float_as_uint(f);
    u += 0x7fffu + ((u >> 16) & 1u);
    return (unsigned short)(u >> 16);
}

__device__ __forceinline__ float fast_exp2(float x) {
#if __has_builtin(__builtin_amdgcn_exp2f)
    return __builtin_amdgcn_exp2f(x);
#else
    return exp2f(x);
#endif
}

// k1: stage tgt bf16 in B-frag order (lane-contiguous 1KB stores/wave), sq_t,
// sq_s, per-block partial sums of (sq_t, psi). No atomics. (Proven in R3/R5.)
__global__ __launch_bounds__(256) void k1_stage(const float* __restrict__ src,
                                                const float* __restrict__ tgt,
                                                const float* __restrict__ psi,
                                                char* __restrict__ ws) {
    const int tid  = threadIdx.x;
    const int wave = tid >> 6;
    const int lane = tid & 63;
    const int lo   = lane & 15;
    const int hi   = lane >> 4;
    const int task = blockIdx.x * 4 + wave;   // 0..1535

    float sq_contrib = 0.f, ps_contrib = 0.f;
    if (task < 1024) {                        // tgt tile
        const int T = task, j = T * 16 + lo;
        float sq = 0.f;
#pragma unroll
        for (int kk = 0; kk < 2; ++kk) {
            const float* p = tgt + (size_t)j * 64 + kk * 32 + hi * 8;
            float4 v0 = ((const float4*)p)[0];
            float4 v1 = ((const float4*)p)[1];
            short8 pk;
            pk[0]=(short)f2bf(v0.x); pk[1]=(short)f2bf(v0.y); pk[2]=(short)f2bf(v0.z); pk[3]=(short)f2bf(v0.w);
            pk[4]=(short)f2bf(v1.x); pk[5]=(short)f2bf(v1.y); pk[6]=(short)f2bf(v1.z); pk[7]=(short)f2bf(v1.w);
            ((short8*)(ws + OFF_TGT))[(T * 2 + kk) * 64 + lane] = pk;
            sq += v0.x*v0.x + v0.y*v0.y + v0.z*v0.z + v0.w*v0.w
                + v1.x*v1.x + v1.y*v1.y + v1.z*v1.z + v1.w*v1.w;
        }
        float r = sq;
        r += __shfl_xor(r, 16); r += __shfl_xor(r, 32);
        if (hi == 0) {
            ((float*)(ws + OFF_SQT))[j] = r;
            ps_contrib = psi[j];
        }
        sq_contrib = sq;
    } else {                                  // src row norms only
        const int i = (task - 1024) * 16 + lo;
        float sq = 0.f;
#pragma unroll
        for (int kk = 0; kk < 2; ++kk) {
            const float* p = src + (size_t)i * 64 + kk * 32 + hi * 8;
            float4 v0 = ((const float4*)p)[0];
            float4 v1 = ((const float4*)p)[1];
            sq += v0.x*v0.x + v0.y*v0.y + v0.z*v0.z + v0.w*v0.w
                + v1.x*v1.x + v1.y*v1.y + v1.z*v1.z + v1.w*v1.w;
        }
        float r = sq;
        r += __shfl_xor(r, 16); r += __shfl_xor(r, 32);
        if (hi == 0) ((float*)(ws + OFF_SQS))[i] = r;
    }

    float a = sq_contrib, bb = ps_contrib;
#pragma unroll
    for (int off = 1; off < 64; off <<= 1) { a += __shfl_xor(a, off); bb += __shfl_xor(bb, off); }
    __shared__ float s_a[4], s_b[4];
    if (lane == 0) { s_a[wave] = a; s_b[wave] = bb; }
    __syncthreads();
    if (tid == 0) {
        float2 o;
        o.x = s_a[0] + s_a[1] + s_a[2] + s_a[3];
        o.y = s_b[0] + s_b[1] + s_b[2] + s_b[3];
        ((float2*)(ws + OFF_PART))[blockIdx.x] = o;
    }
}

// k2: MFMA GEMM + sum-exp2. 2048 blocks: 64 rows x 1024 cols each; per wave
// 16 col-tiles, depth-1 register prefetch from L2. Bias enters as the MFMA C
// operand; alpha2 folded into bf16 A-fragments. (Math verified in R5.)
__global__ __launch_bounds__(256) void k2_main(const float* __restrict__ src,
                                               const float* __restrict__ psi,
                                               char* __restrict__ ws) {
    const int tid  = threadIdx.x;
    const int lane = tid & 63;
    const int w    = tid >> 6;
    const int lo   = lane & 15;
    const int hi   = lane >> 4;
    const int q      = blockIdx.x & (QSPLIT - 1);
    const int rowblk = blockIdx.x >> 4;
    const int row0   = rowblk * 64;

    __shared__ float s_bias[1024];   // this block's 1024-col bias (exp2 domain)
    __shared__ float s_l[4][64];

    // sum sq_t from k1 partials (384 entries, 6 per lane)
    const float2* __restrict__ part = (const float2*)(ws + OFF_PART);
    float ssq = 0.f;
#pragma unroll
    for (int k = 0; k < K1_BLOCKS / 64; ++k) ssq += part[k * 64 + lane].x;
#pragma unroll
    for (int off = 1; off < 64; off <<= 1) ssq += __shfl_xor(ssq, off);
    const float inv_cn = (float)M_TGT / ssq;
    const float c_psi  = (1.0f / REG_P) * LOG2E;
    const float c_sqt  = inv_cn * c_psi;
    const float alpha2 = 2.0f * c_sqt;

    // A fragments from global fp32, pre-scaled by alpha2
    short8 Af[4][2];
#pragma unroll
    for (int g = 0; g < 4; ++g)
#pragma unroll
        for (int kk = 0; kk < 2; ++kk) {
            const float* p = src + (size_t)(row0 + g * 16 + lo) * 64 + kk * 32 + hi * 8;
            float4 u0 = ((const float4*)p)[0];
            float4 u1 = ((const float4*)p)[1];
            short8 pk;
            pk[0]=(short)f2bf(alpha2*u0.x); pk[1]=(short)f2bf(alpha2*u0.y);
            pk[2]=(short)f2bf(alpha2*u0.z); pk[3]=(short)f2bf(alpha2*u0.w);
            pk[4]=(short)f2bf(alpha2*u1.x); pk[5]=(short)f2bf(alpha2*u1.y);
            pk[6]=(short)f2bf(alpha2*u1.z); pk[7]=(short)f2bf(alpha2*u1.w);
            Af[g][kk] = pk;
        }

    // bias table for this block's 1024 cols: 4 floats per thread
    {
        const float* SQT = (const float*)(ws + OFF_SQT);
        const int j0 = q * 1024 + tid * 4;
        float4 sa = *(const float4*)(SQT + j0);
        float4 pa = *(const float4*)(psi + j0);
        float4 o0;
        o0.x = pa.x * c_psi - sa.x * c_sqt;  o0.y = pa.y * c_psi - sa.y * c_sqt;
        o0.z = pa.z * c_psi - sa.z * c_sqt;  o0.w = pa.w * c_psi - sa.w * c_sqt;
        *(float4*)&s_bias[tid * 4] = o0;
    }
    __syncthreads();

    float lsum[4][4];
#pragma unroll
    for (int g = 0; g < 4; ++g)
#pragma unroll
        for (int r = 0; r < 4; ++r) lsum[g][r] = 0.f;

    const short8* __restrict__ TG = (const short8*)(ws + OFF_TGT);
    const int Tbase = q * 64 + w * 16;   // this wave's 16 global col-tiles
    const int colb  = w * 256 + lo;      // LDS bias base

    short8 B0n = TG[(Tbase * 2 + 0) * 64 + lane];
    short8 B1n = TG[(Tbase * 2 + 1) * 64 + lane];
    float  bln = s_bias[colb];

    for (int t = 0; t < 16; ++t) {
        short8 B0 = B0n, B1 = B1n;
        float  bl = bln;
        if (t < 15) {
            B0n = TG[((Tbase + t + 1) * 2 + 0) * 64 + lane];
            B1n = TG[((Tbase + t + 1) * 2 + 1) * 64 + lane];
            bln = s_bias[colb + (t + 1) * 16];
        }
        f32x4 bias4 = {bl, bl, bl, bl};   // C operand: bias per col (col = lane&15)
        f32x4 acc[4];
#pragma unroll
        for (int g = 0; g < 4; ++g) {
            f32x4 a = __builtin_amdgcn_mfma_f32_16x16x32_bf16(Af[g][0], B0, bias4, 0, 0, 0);
            a       = __builtin_amdgcn_mfma_f32_16x16x32_bf16(Af[g][1], B1, a,     0, 0, 0);
            acc[g] = a;
        }
#pragma unroll
        for (int g = 0; g < 4; ++g)
#pragma unroll
            for (int r = 0; r < 4; ++r)
                lsum[g][r] += fast_exp2(acc[g][r]);
    }

    // reduce over 16 col-lanes per row; combine 4 waves via LDS; write q-slice
#pragma unroll
    for (int g = 0; g < 4; ++g)
#pragma unroll
        for (int r = 0; r < 4; ++r) {
            float v = lsum[g][r];
            v += __shfl_xor(v, 1); v += __shfl_xor(v, 2);
            v += __shfl_xor(v, 4); v += __shfl_xor(v, 8);
            if ((lane & 15) == 0) s_l[w][g * 16 + (lane >> 4) * 4 + r] = v;
        }
    __syncthreads();
    if (tid < 64) {
        float v = s_l[0][tid] + s_l[1][tid] + s_l[2][tid] + s_l[3][tid];
        ((float*)(ws + OFF_L))[q * N_SRC + row0 + tid] = v;
    }
}

// k3: combine q-slices, lse, scalar.
__global__ __launch_bounds__(1024) void k3_final(const char* __restrict__ ws,
                                                 float* __restrict__ out) {
    const int tid = threadIdx.x;
    const float2* __restrict__ part = (const float2*)(ws + OFF_PART);
    float ssq = 0.f, spsi = 0.f;
#pragma unroll
    for (int k = 0; k < K1_BLOCKS / 64; ++k) {
        float2 p = part[k * 64 + (tid & 63)];
        ssq += p.x; spsi += p.y;
    }
#pragma unroll
    for (int off = 1; off < 64; off <<= 1) {
        ssq  += __shfl_xor(ssq, off);
        spsi += __shfl_xor(spsi, off);
    }
    const float inv_cn = (float)M_TGT / ssq;
    const float* __restrict__ L   = (const float*)(ws + OFF_L);
    const float* __restrict__ sqs = (const float*)(ws + OFF_SQS);
    const float logM = logf((float)M_TGT);
    float acc = 0.f;
    for (int i = tid; i < N_SRC; i += 1024) {
        float lt = 0.f;
#pragma unroll
        for (int qq = 0; qq < QSPLIT; ++qq) lt += L[qq * N_SRC + i];
        const float A = -sqs[i] * inv_cn * (1.0f / REG_P) - logM;
        acc += -REG_P * (A + LN2 * __log2f(lt));
    }
    __shared__ float red[1024];
    red[tid] = acc;
    __syncthreads();
    for (int off = 512; off > 0; off >>= 1) {
        if (tid < off) red[tid] += red[tid + off];
        __syncthreads();
    }
    if (tid == 0)
        out[0] = red[0] / (float)N_SRC + spsi / (float)M_TGT;
}

extern "C" void kernel_launch(void* const* d_in, const int* in_sizes, int n_in,
                              void* d_out, int out_size, void* d_ws, size_t ws_size,
                              hipStream_t stream) {
    const float* src = (const float*)d_in[0];   // [N, D]
    const float* tgt = (const float*)d_in[1];   // [M, D]
    const float* psi = (const float*)d_in[2];   // [M]
    char*  ws  = (char*)d_ws;
    float* out = (float*)d_out;

    k1_stage<<<K1_BLOCKS, 256, 0, stream>>>(src, tgt, psi, ws);
    k2_main<<<(N_SRC / 64) * QSPLIT, 256, 0, stream>>>(src, psi, ws);
    k3_final<<<1, 1024, 0, stream>>>(ws, out);
}